// Round 9
// baseline (886.727 us; speedup 1.0000x reference)
//
#include <hip/hip_runtime.h>

#define B_ 32
#define S_ 2048
#define D_ 128
#define NT 32   // S_/64 kv tiles
#define QB 256  // q rows per block

typedef __bf16 bf16;
typedef unsigned u32;
typedef unsigned long long u64;
typedef __attribute__((ext_vector_type(8))) __bf16 bf16x8;
typedef __attribute__((ext_vector_type(16))) float f32x16;

__device__ __forceinline__ f32x16 mfma32(bf16x8 a, bf16x8 b, f32x16 c) {
  return __builtin_amdgcn_mfma_f32_32x32x16_bf16(a, b, c, 0, 0, 0);
}

__device__ __forceinline__ u32 pk2(bf16 a, bf16 b) {
  unsigned short ua = __builtin_bit_cast(unsigned short, a);
  unsigned short ub = __builtin_bit_cast(unsigned short, b);
  return (u32)ua | ((u32)ub << 16);
}

// async global->LDS, 16B per lane; lds dst must be wave-uniform base
__device__ __forceinline__ void glds16(const bf16* g, char* l) {
  __builtin_amdgcn_global_load_lds(
      (const __attribute__((address_space(1))) void*)g,
      (__attribute__((address_space(3))) void*)l, 16, 0, 0);
}

// ---------------------------------------------------------------------------
// K pre-pass: K [B][S][D] fp32 -> hi/lo bf16, tile-contiguous [b*NT+kt][64][128]
// with the attention QK LDS read swizzle pre-baked: source 16B chunk c of row
// kr stored at chunk c ^ (kr & 15). Attn staging is then a pure linear copy.
// ---------------------------------------------------------------------------
__global__ __launch_bounds__(256) void k_prepass(const float* __restrict__ K,
                                                 bf16* __restrict__ khi,
                                                 bf16* __restrict__ klo) {
  const int bid = blockIdx.x;  // = b*NT + kt (K rows are tile-contiguous)
  const int t = threadIdx.x;
  const int kr = t >> 2;
  const int cbase = (t & 3) * 4;
  const float* src = K + (size_t)bid * 8192 + kr * 128;
  bf16* ho = khi + (size_t)bid * 8192 + kr * 128;
  bf16* lo = klo + (size_t)bid * 8192 + kr * 128;
  const int swz = kr & 15;
#pragma unroll
  for (int j = 0; j < 4; ++j) {
    const int c = cbase + j;
    float4 a = *(const float4*)(src + c * 8);
    float4 b2 = *(const float4*)(src + c * 8 + 4);
    float f[8] = {a.x, a.y, a.z, a.w, b2.x, b2.y, b2.z, b2.w};
    bf16x8 h8, l8;
#pragma unroll
    for (int e = 0; e < 8; ++e) {
      bf16 hi = (bf16)f[e];
      h8[e] = hi;
      l8[e] = (bf16)(f[e] - (float)hi);
    }
    *(bf16x8*)(ho + (c ^ swz) * 8) = h8;
    *(bf16x8*)(lo + (c ^ swz) * 8) = l8;
  }
}

// ---------------------------------------------------------------------------
// V pre-pass: V [B][S][D] fp32 -> VT hi/lo bf16, tile-contiguous
// [b*NT+kt][d][64k], source k-chunk c stored at chunk c ^ (d & 7).
// ---------------------------------------------------------------------------
__global__ __launch_bounds__(256) void vt_prepass(const float* __restrict__ V,
                                                  bf16* __restrict__ vthi,
                                                  bf16* __restrict__ vtlo) {
  const int bid = blockIdx.x;
  const int b = bid >> 5, kt = bid & 31;
  const int kbase = kt * 64;
  const int t = threadIdx.x;
  __shared__ u32 Tpk[128][67];  // packed (hi | lo<<16), odd word stride

  {
    const int dc = t & 31, kr0 = t >> 5;
#pragma unroll
    for (int i = 0; i < 8; ++i) {
      const int kr = kr0 + i * 8;
      float4 v = *(const float4*)(V + ((size_t)b * S_ + kbase + kr) * D_ + dc * 4);
      float f[4] = {v.x, v.y, v.z, v.w};
#pragma unroll
      for (int j = 0; j < 4; ++j) {
        bf16 hi = (bf16)f[j];
        bf16 lo = (bf16)(f[j] - (float)hi);
        Tpk[dc * 4 + j][kr] = pk2(hi, lo);
      }
    }
  }
  __syncthreads();
#pragma unroll
  for (int p = 0; p < 4; ++p) {
    const int g = p * 256 + t;
    const int d = g >> 3, c = g & 7;
    const int cs = c ^ (d & 7);
    u32 wv[8];
#pragma unroll
    for (int e = 0; e < 8; ++e) wv[e] = Tpk[d][cs * 8 + e];
    uint4 hi4, lo4;
    u32* hp = (u32*)&hi4;
    u32* lp = (u32*)&lo4;
#pragma unroll
    for (int j = 0; j < 4; ++j) {
      hp[j] = (wv[2 * j] & 0xffffu) | (wv[2 * j + 1] << 16);
      lp[j] = (wv[2 * j] >> 16) | (wv[2 * j + 1] & 0xffff0000u);
    }
    const size_t base = ((size_t)(b * NT + kt) * 128 + d) * 64 + c * 8;
    *(uint4*)(vthi + base) = hi4;
    *(uint4*)(vtlo + base) = lo4;
  }
}

// ---------------------------------------------------------------------------
// Flash attention: 8 waves x 32 q = 256 q/block, KV tile 64, grid 256 =
// 1 block/CU, 2 waves/SIMD. Double-buffered LDS 128KB; per-tile schedule:
//   issue mask loads (this tile) -> issue glds16 (next tile, other buffer)
//   -> QK^T -> ballot mask -> online softmax -> PV -> one barrier.
// Staging latency hides under ~2000 cycles of compute (T3-minimal 2-phase).
// Per buffer: Khi 16K | Klo 16K | VThi 16K | VTlo 16K.
// ---------------------------------------------------------------------------
__global__ __launch_bounds__(512, 2) void attn_kernel(
    const float* __restrict__ Q, const int* __restrict__ M,
    const bf16* __restrict__ khi_g, const bf16* __restrict__ klo_g,
    const bf16* __restrict__ vthi_g, const bf16* __restrict__ vtlo_g,
    float* __restrict__ Out) {
  extern __shared__ char smem[];
  const int t = threadIdx.x;
  const int w = t >> 6;        // wave 0..7
  const int lane = t & 63;
  const int i31 = t & 31;
  const int h = (t >> 5) & 1;

  // XCD swizzle: 256 blocks = 1/CU; 4 batches per XCD
  const int bid = blockIdx.x;
  const int slot = bid >> 3;
  const int b = (bid & 7) * 4 + (slot >> 3);
  const int qbase = (slot & 7) * QB;
  const int qloc = w * 32 + i31;

  // ---- Q fragments (scale*log2e folded, hi/lo split) ----
  const float sc = 0.08838834764831843f * 1.4426950408889634f;
  bf16x8 qh[8], ql[8];
  {
    const float* qsrc = Q + ((size_t)b * S_ + qbase + qloc) * D_;
#pragma unroll
    for (int ds = 0; ds < 8; ++ds) {
      const int d0 = ds * 16 + h * 8;
      float4 a = *(const float4*)(qsrc + d0);
      float4 c = *(const float4*)(qsrc + d0 + 4);
      float f[8] = {a.x, a.y, a.z, a.w, c.x, c.y, c.z, c.w};
#pragma unroll
      for (int e = 0; e < 8; ++e) {
        float v = f[e] * sc;
        bf16 hi = (bf16)v;
        qh[ds][e] = hi;
        ql[ds][e] = (bf16)(v - (float)hi);
      }
    }
  }

  f32x16 acc[4];
#pragma unroll
  for (int dt = 0; dt < 4; ++dt)
#pragma unroll
    for (int e = 0; e < 16; ++e) acc[dt][e] = 0.f;
  float m_run = -3.0e38f, l_run = 0.f;

  // wave w stages half (w&1) of region (w>>1): 0=Khi 1=Klo 2=VThi 3=VTlo
  const int reg = w >> 1, half = w & 1;
  const bf16* gsel = (reg == 0) ? khi_g : (reg == 1) ? klo_g
                     : (reg == 2) ? vthi_g : vtlo_g;
  const bf16* gsrc0 = gsel + (size_t)(b * NT) * 8192 + half * 4096 + lane * 8;
  const u32 lbase = (u32)(reg * 16384 + half * 8192);

  // mask row pointer (lane = k column within tile)
  const int* mptr = M + ((size_t)b * S_ + qbase + w * 32) * S_ + lane;

  // ---- prologue: stage tile 0 into buffer 0 ----
#pragma unroll
  for (int i = 0; i < 8; ++i) glds16(gsrc0 + i * 512, smem + lbase + i * 1024);
  __syncthreads();  // drains glds

#pragma unroll 1
  for (int kt = 0; kt < NT; ++kt) {
    const int cb = kt & 1;
    const char* kb = smem + cb * 65536;

    // ---- issue this tile's mask loads (consumed after QK) ----
    int mv[32];
    {
      const int knb = kt * 64;
#pragma unroll
      for (int r = 0; r < 32; ++r) mv[r] = mptr[r * S_ + knb];
    }
    // ---- issue next tile's staging into the other buffer ----
    if (kt + 1 < NT) {
      const bf16* gsrc = gsrc0 + (size_t)(kt + 1) * 8192;
      char* ldst = smem + (cb ^ 1) * 65536 + lbase;
#pragma unroll
      for (int i = 0; i < 8; ++i) glds16(gsrc + i * 512, ldst + i * 1024);
    }

    // ---- QK^T (S^T = K * Q): hi*hi + lo*hi + hi*lo ----
    f32x16 s[2];
#pragma unroll
    for (int ct = 0; ct < 2; ++ct)
#pragma unroll
      for (int e = 0; e < 16; ++e) s[ct][e] = 0.f;
    __builtin_amdgcn_s_setprio(1);
#pragma unroll
    for (int ct = 0; ct < 2; ++ct) {
      const u32 rowb = (u32)(ct * 32 + i31) * 256;
      const u32 sw = (u32)(i31 & 15);
#pragma unroll
      for (int ds = 0; ds < 8; ++ds) {
        const u32 off = rowb + (((u32)(ds * 2 + h) ^ sw) * 16);
        bf16x8 kh = *(const bf16x8*)(kb + off);
        bf16x8 kl = *(const bf16x8*)(kb + 16384 + off);
        s[ct] = mfma32(kh, qh[ds], s[ct]);
        s[ct] = mfma32(kl, qh[ds], s[ct]);
        s[ct] = mfma32(kh, ql[ds], s[ct]);
      }
    }
    __builtin_amdgcn_s_setprio(0);

    // ---- build per-lane mask bits (ballots; loads landed during QK) ----
    u64 mc = 0;
#pragma unroll
    for (int r = 0; r < 32; ++r) {
      const u64 bal = __ballot(mv[r] != 0);
      if (i31 == r) mc = bal;
    }

    // ---- online softmax (log2 domain); mask -> p = 0 after exp ----
    float mx = -3.0e38f;
#pragma unroll
    for (int ct = 0; ct < 2; ++ct)
#pragma unroll
      for (int r = 0; r < 16; ++r) mx = fmaxf(mx, s[ct][r]);
    mx = fmaxf(mx, __shfl_xor(mx, 32, 64));
    const float m_new = fmaxf(m_run, mx);
    const float alpha = exp2f(m_run - m_new);
    const u32 mw0 = (u32)mc, mw1 = (u32)(mc >> 32);
    float rs = 0.f;
#pragma unroll
    for (int ct = 0; ct < 2; ++ct) {
      const u32 mword = ct ? mw1 : mw0;
#pragma unroll
      for (int r = 0; r < 16; ++r) {
        const int pos = (r & 3) + 8 * (r >> 2) + 4 * h;
        float p = exp2f(s[ct][r] - m_new);
        p = ((mword >> pos) & 1u) ? p : 0.f;
        s[ct][r] = p;
        rs += p;
      }
    }
    rs += __shfl_xor(rs, 32, 64);
    l_run = l_run * alpha + rs;
    m_run = m_new;
#pragma unroll
    for (int dt = 0; dt < 4; ++dt) acc[dt] = acc[dt] * alpha;

    // ---- PV: O^T += VT * P^T, P^T frags built in-register ----
    __builtin_amdgcn_s_setprio(1);
#pragma unroll
    for (int ks = 0; ks < 4; ++ks) {
      const int ct = ks >> 1;
      const int a0 = (ks & 1) * 8;
      u32 PKh[4], PKl[4];
#pragma unroll
      for (int y = 0; y < 4; ++y) {
        const float p0 = s[ct][a0 + 2 * y];
        const float p1 = s[ct][a0 + 2 * y + 1];
        bf16 h0 = (bf16)p0, h1 = (bf16)p1;
        PKh[y] = pk2(h0, h1);
        PKl[y] = pk2((bf16)(p0 - (float)h0), (bf16)(p1 - (float)h1));
      }
      const u32 s0h = h ? PKh[0] : PKh[2];
      const u32 s1h = h ? PKh[1] : PKh[3];
      const u32 s0l = h ? PKl[0] : PKl[2];
      const u32 s1l = h ? PKl[1] : PKl[3];
      const u32 r0h = __shfl_xor(s0h, 32, 64);
      const u32 r1h = __shfl_xor(s1h, 32, 64);
      const u32 r0l = __shfl_xor(s0l, 32, 64);
      const u32 r1l = __shfl_xor(s1l, 32, 64);
      uint4 fh, fl;
      fh.x = h ? r0h : PKh[0];
      fh.y = h ? r1h : PKh[1];
      fh.z = h ? PKh[2] : r0h;
      fh.w = h ? PKh[3] : r1h;
      fl.x = h ? r0l : PKl[0];
      fl.y = h ? r1l : PKl[1];
      fl.z = h ? PKl[2] : r0l;
      fl.w = h ? PKl[3] : r1l;
      bf16x8 pah = __builtin_bit_cast(bf16x8, fh);
      bf16x8 pal = __builtin_bit_cast(bf16x8, fl);
#pragma unroll
      for (int dt = 0; dt < 4; ++dt) {
        const u32 d = (u32)(dt * 32 + i31);
        const u32 off = d * 128 + ((((u32)(ks * 2 + h)) ^ (d & 7)) * 16);
        bf16x8 vh = *(const bf16x8*)(kb + 32768 + off);
        bf16x8 vl = *(const bf16x8*)(kb + 49152 + off);
        acc[dt] = mfma32(vh, pah, acc[dt]);
        acc[dt] = mfma32(vh, pal, acc[dt]);
        acc[dt] = mfma32(vl, pah, acc[dt]);
      }
    }
    __builtin_amdgcn_s_setprio(0);

    // ---- one barrier: drains next-tile glds (issued ~2000 cyc ago) and
    //      protects buf[cb] before iteration kt+2 restages it ----
    __syncthreads();
  }

  // ---- epilogue ----
  const float inv_l = 1.0f / l_run;
  float* orow = Out + ((size_t)b * S_ + qbase + qloc) * D_;
#pragma unroll
  for (int dt = 0; dt < 4; ++dt) {
#pragma unroll
    for (int rr = 0; rr < 4; ++rr) {
      float4 o;
      o.x = acc[dt][rr * 4 + 0] * inv_l;
      o.y = acc[dt][rr * 4 + 1] * inv_l;
      o.z = acc[dt][rr * 4 + 2] * inv_l;
      o.w = acc[dt][rr * 4 + 3] * inv_l;
      *(float4*)(orow + dt * 32 + rr * 8 + h * 4) = o;
    }
  }
}

extern "C" void kernel_launch(void* const* d_in, const int* in_sizes, int n_in,
                              void* d_out, int out_size, void* d_ws,
                              size_t ws_size, hipStream_t stream) {
  (void)in_sizes; (void)n_in; (void)out_size; (void)ws_size;
  const float* Q = (const float*)d_in[0];
  const float* K = (const float*)d_in[1];
  const float* V = (const float*)d_in[2];
  const int* M = (const int*)d_in[3];
  float* Out = (float*)d_out;

  const size_t el = (size_t)B_ * S_ * D_;  // 8.39M
  bf16* khi = (bf16*)d_ws;                 // 16.78 MB each
  bf16* klo = khi + el;
  bf16* vthi = klo + el;
  bf16* vtlo = vthi + el;

  static int attr_set = 0;
  if (!attr_set) {
    hipFuncSetAttribute((const void*)attn_kernel,
                        hipFuncAttributeMaxDynamicSharedMemorySize, 131072);
    attr_set = 1;
  }

  k_prepass<<<dim3(B_ * NT), dim3(256), 0, stream>>>(K, khi, klo);
  vt_prepass<<<dim3(B_ * NT), dim3(256), 0, stream>>>(V, vthi, vtlo);
  attn_kernel<<<dim3(256), dim3(512), 131072, stream>>>(Q, M, khi, klo, vthi,
                                                        vtlo, Out);
}